// Round 8
// baseline (367.454 us; speedup 1.0000x reference)
//
#include <hip/hip_runtime.h>
#include <hip/hip_bf16.h>
#include <math.h>

#define B_ 2
#define N_ 768
#define T_ 96
#define FM_ 8
#define HID_ 64
#define TD_ 32
#define MD_ 32
#define TILE 16
#define TI32 32
#define NTILES (N_/TILE)            // 48
#define PERB 600                    // sum_{a=0}^{23} (48-2a)
#define NPAIRT (B_*PERB)            // 1200
#define NFEAT 386                   // 384 row-groups + 2 wd-pack groups
#define NROWS (B_*N_)               // 1536
#define SJSTR 66
#define GRID_ 512                   // 2 blocks/CU x 256 CUs, co-resident by construction

typedef __attribute__((ext_vector_type(8))) short short8v;
typedef __attribute__((ext_vector_type(4))) float f32x4;
typedef __attribute__((ext_vector_type(2))) float f32x2;
typedef __attribute__((ext_vector_type(4))) unsigned int uint4v;

__device__ __forceinline__ unsigned int pack_bf2(float d0, float d1){
  __hip_bfloat162 t = __float22bfloat162_rn(make_float2(d0, d1));
  unsigned int u;
  __builtin_memcpy(&u, &t, 4);
  return u;
}

__device__ __forceinline__ float ftanh(float x){
  float e = __expf(2.f * x);
  return 1.f - 2.f * __builtin_amdgcn_rcpf(e + 1.f);
}

__device__ __forceinline__ float wave_sum64(float v){
  #pragma unroll
  for (int m = 32; m; m >>= 1) v += __shfl_xor(v, m);
  return v;
}
__device__ __forceinline__ float wave_max64(float v){
  #pragma unroll
  for (int m = 32; m; m >>= 1) v = fmaxf(v, __shfl_xor(v, m));
  return v;
}

// Grid-wide barrier: all GRID_ blocks are co-resident (launch_bounds-guaranteed
// 2 blocks/CU). ctr must be zeroed before launch (hipMemsetAsync node).
__device__ __forceinline__ void grid_barrier(unsigned int* ctr){
  __syncthreads();
  if (threadIdx.x == 0) {
    __threadfence();   // agent-scope release of all prior writes
    __hip_atomic_fetch_add(ctr, 1u, __ATOMIC_ACQ_REL, __HIP_MEMORY_SCOPE_AGENT);
    while (__hip_atomic_load(ctr, __ATOMIC_ACQUIRE, __HIP_MEMORY_SCOPE_AGENT) < (unsigned)GRID_) {
      __builtin_amdgcn_s_sleep(8);
    }
    __threadfence();   // agent-scope acquire before dependent reads
  }
  __syncthreads();
}

// ---------------------------------------------------------------------------
// Megakernel: phase A (feat + wd pack) -> barrier -> phase B (pair tiles)
// -> barrier -> phase C (normalize rows). All phases grid-strided.
// ---------------------------------------------------------------------------
__global__ __launch_bounds__(256, 2) void mega_kernel(
    const float* __restrict__ x_hist, const float* __restrict__ x_mark,
    const float* __restrict__ te_w1, const float* __restrict__ te_b1,
    const float* __restrict__ te_w2, const float* __restrict__ te_b2,
    const float* __restrict__ me_w1, const float* __restrict__ me_b1,
    const float* __restrict__ me_w2, const float* __restrict__ me_b2,
    const float* __restrict__ nf_w,  const float* __restrict__ nf_b,
    const float* __restrict__ ps_w1, const float* __restrict__ ps_b1,
    const float* __restrict__ ps_w2, const float* __restrict__ ps_b2,
    const float* __restrict__ raw_lambda, const float* __restrict__ a_static,
    float* __restrict__ out,
    float* __restrict__ h, float* __restrict__ si, float* __restrict__ sj,
    unsigned short* __restrict__ wdf, unsigned int* __restrict__ bar)
{
  __shared__ union {
    struct {
      float st[4][3]; float ms[4][FM_]; float t1s[4][TD_]; float m1s[4][MD_];
      float hc[4][HID_]; float hs[4][HID_];
    } f;
    struct {
      float hI[TI32][HID_];
      float hJT[HID_][TILE + 1];
      f32x2 SI2[TI32][HID_];
      f32x2 SJ2[TILE][SJSTR];
    } p;
    struct { float ps[4]; } n;
  } sh;

  const int tid  = threadIdx.x;
  const int lane = tid & 63;
  const int w    = tid >> 6;

  // ===================== Phase A: features =====================
  for (int u = blockIdx.x; u < NFEAT; u += GRID_) {
    if (u >= NROWS / 4) {               // wd-pack groups (u = 384, 385)
      const int q  = (u - NROWS / 4) * 4 + w;   // 0..7 = nt*2+s
      const int nt = q >> 1, s = q & 1;
      const int col = (lane & 15) + 16 * nt;
      const int k0  = s * 32 + ((lane >> 4) << 3);
      #pragma unroll
      for (int jj = 0; jj < 8; ++jj) {
        float v = ps_w1[(2 * HID_ + k0 + jj) * HID_ + col];
        __hip_bfloat16 bv = __float2bfloat16(v);
        unsigned short us;
        __builtin_memcpy(&us, &bv, 2);
        wdf[(q * 64 + lane) * 8 + jj] = us;
      }
      continue;
    }
    const int row = u * 4 + w;          // b*N + n

    const float* xh = x_hist + (long)row * T_;
    float s  = xh[lane];
    float mx = s;
    if (lane < T_ - 64) { float v = xh[lane + 64]; s += v; mx = fmaxf(mx, v); }
    s  = wave_sum64(s);
    mx = wave_max64(mx);
    if (lane == 0) { sh.f.st[w][0] = xh[T_ - 1]; sh.f.st[w][1] = s * (1.0f / T_); sh.f.st[w][2] = mx; }

    const float* xm = x_mark + (long)row * T_ * FM_;
    float msv = 0.f;
    #pragma unroll
    for (int k = 0; k < 12; ++k) msv += xm[lane + 64 * k];
    msv += __shfl_xor(msv, 8);
    msv += __shfl_xor(msv, 16);
    msv += __shfl_xor(msv, 32);
    if (lane < FM_) sh.f.ms[w][lane] = msv * (1.0f / T_);
    __syncthreads();

    if (lane < TD_) {
      float a = te_b1[lane];
      #pragma unroll
      for (int k = 0; k < 3; ++k) a += sh.f.st[w][k] * te_w1[k * TD_ + lane];
      sh.f.t1s[w][lane] = fmaxf(a, 0.f);
      float am = me_b1[lane];
      #pragma unroll
      for (int k = 0; k < FM_; ++k) am += sh.f.ms[w][k] * me_w1[k * MD_ + lane];
      sh.f.m1s[w][lane] = fmaxf(am, 0.f);
    }
    __syncthreads();
    if (lane < TD_) {
      float a = te_b2[lane];
      #pragma unroll
      for (int k = 0; k < TD_; ++k) a += sh.f.t1s[w][k] * te_w2[k * TD_ + lane];
      sh.f.hc[w][lane] = a;
      float am = me_b2[lane];
      #pragma unroll
      for (int k = 0; k < MD_; ++k) am += sh.f.m1s[w][k] * me_w2[k * MD_ + lane];
      sh.f.hc[w][TD_ + lane] = am;
    }
    __syncthreads();
    {
      float a = nf_b[lane];
      #pragma unroll
      for (int k = 0; k < HID_; ++k) a += sh.f.hc[w][k] * nf_w[k * HID_ + lane];
      float hv = fmaxf(a, 0.f);
      sh.f.hs[w][lane] = hv;
      h[(long)row * HID_ + lane] = hv;
    }
    __syncthreads();
    {
      float a1 = 0.f, a2 = 0.f;
      #pragma unroll
      for (int k = 0; k < HID_; ++k) {
        float hv = sh.f.hs[w][k];
        a1 += hv * ps_w1[k * HID_ + lane];
        a2 += hv * ps_w1[(HID_ + k) * HID_ + lane];
      }
      si[(long)row * HID_ + lane] = a1;
      sj[(long)row * HID_ + lane] = a2;
    }
    __syncthreads();
  }

  grid_barrier(bar + 0);

  // ===================== Phase B: pair tiles =====================
  for (int tt = blockIdx.x; tt < NPAIRT; tt += GRID_) {
    int b = tt / PERB;
    int t = tt % PERB;
    int a = 0;
    while (t >= NTILES - 2 * a) { t -= NTILES - 2 * a; ++a; }
    int tJ = 2 * a + t;
    const int i0 = a * TI32, j0 = tJ * TILE;

    {
      const int r  = tid >> 4;        // 0..15
      const int c4 = (tid & 15) * 4;
      const f32x4 b14 = *(const f32x4*)(ps_b1 + c4);
      #pragma unroll
      for (int p = 0; p < 2; ++p) {
        const int rr = r + p * 16;
        const long gi = ((long)b * N_ + i0 + rr) * HID_ + c4;
        *(f32x4*)&sh.p.hI[rr][c4] = *(const f32x4*)(h + gi);
        f32x4 vii = *(const f32x4*)(si + gi) + b14;
        f32x4 vji = *(const f32x4*)(sj + gi);
        #pragma unroll
        for (int q = 0; q < 4; ++q) sh.p.SI2[rr][c4 + q] = (f32x2){vii[q], vji[q]};
      }
      const long gj = ((long)b * N_ + j0 + r) * HID_ + c4;
      f32x4 vhj = *(const f32x4*)(h + gj);
      #pragma unroll
      for (int q = 0; q < 4; ++q) sh.p.hJT[c4 + q][r] = vhj[q];
      f32x4 vij = *(const f32x4*)(si + gj) + b14;
      f32x4 vjj = *(const f32x4*)(sj + gj);
      #pragma unroll
      for (int q = 0; q < 4; ++q) sh.p.SJ2[r][c4 + q] = (f32x2){vjj[q], vij[q]};
    }
    const float b2 = ps_b2[0];
    __syncthreads();

    const int g   = lane >> 4;     // 0..3
    const int c16 = lane & 15;     // = j within tile

    short8v wfr[8];
    const short8v* wdp = (const short8v*)wdf;
    #pragma unroll
    for (int q = 0; q < 8; ++q) wfr[q] = wdp[q * 64 + lane];

    float hJv[2][8];
    #pragma unroll
    for (int s = 0; s < 2; ++s)
      #pragma unroll
      for (int jj = 0; jj < 8; ++jj)
        hJv[s][jj] = sh.p.hJT[32 * s + 8 * g + jj][c16];

    f32x2 sJ2h[16];
    float w2h[16];
    #pragma unroll
    for (int mt = 0; mt < 4; ++mt) {
      const int cb = 16 * mt + 4 * g;
      f32x4 u0 = *(const f32x4*)&sh.p.SJ2[c16][cb];
      f32x4 u1 = *(const f32x4*)&sh.p.SJ2[c16][cb + 2];
      sJ2h[mt*4+0] = (f32x2){u0[0], u0[1]};
      sJ2h[mt*4+1] = (f32x2){u0[2], u0[3]};
      sJ2h[mt*4+2] = (f32x2){u1[0], u1[1]};
      sJ2h[mt*4+3] = (f32x2){u1[2], u1[3]};
      #pragma unroll
      for (int r = 0; r < 4; ++r) w2h[mt*4+r] = ps_w2[cb + r];
    }

    float* drow = out + (long)b * N_ * N_;

    #pragma unroll
    for (int m = 0; m < 8; ++m) {
      const int iloc = w * 8 + m;
      const int i = i0 + iloc;

      short8v afr[2];
      #pragma unroll
      for (int s = 0; s < 2; ++s) {
        f32x4 ha = *(const f32x4*)&sh.p.hI[iloc][32 * s + 8 * g];
        f32x4 hb = *(const f32x4*)&sh.p.hI[iloc][32 * s + 8 * g + 4];
        uint4v uv;
        #pragma unroll
        for (int p = 0; p < 2; ++p) {
          float d0 = fabsf(ha[2*p]   - hJv[s][2*p]);
          float d1 = fabsf(ha[2*p+1] - hJv[s][2*p+1]);
          uv[p] = pack_bf2(d0, d1);
        }
        #pragma unroll
        for (int p = 0; p < 2; ++p) {
          float d0 = fabsf(hb[2*p]   - hJv[s][4 + 2*p]);
          float d1 = fabsf(hb[2*p+1] - hJv[s][4 + 2*p+1]);
          uv[2 + p] = pack_bf2(d0, d1);
        }
        afr[s] = __builtin_bit_cast(short8v, uv);
      }

      f32x4 acc[4];
      #pragma unroll
      for (int mt = 0; mt < 4; ++mt) acc[mt] = (f32x4){0.f, 0.f, 0.f, 0.f};
      #pragma unroll
      for (int s = 0; s < 2; ++s)
        #pragma unroll
        for (int mt = 0; mt < 4; ++mt)
          acc[mt] = __builtin_amdgcn_mfma_f32_16x16x32_bf16(wfr[2 * mt + s], afr[s], acc[mt], 0, 0, 0);

      f32x2 acc2 = (f32x2){0.f, 0.f};
      #pragma unroll
      for (int mt = 0; mt < 4; ++mt) {
        const int cb = 16 * mt + 4 * g;
        f32x4 s01 = *(const f32x4*)&sh.p.SI2[iloc][cb];
        f32x4 s23 = *(const f32x4*)&sh.p.SI2[iloc][cb + 2];
        #pragma unroll
        for (int r = 0; r < 4; ++r) {
          f32x2 siv = (r < 2) ? (f32x2){s01[2*r], s01[2*r+1]}
                              : (f32x2){s23[2*(r-2)], s23[2*(r-2)+1]};
          float av = acc[mt][r];
          f32x2 pre = siv + sJ2h[mt*4+r];
          pre = pre + (f32x2){av, av};
          pre = __builtin_elementwise_max(pre, (f32x2){0.f, 0.f});
          acc2 = acc2 + pre * (f32x2){w2h[mt*4+r], w2h[mt*4+r]};
        }
      }
      float a1 = acc2[0], a2 = acc2[1];
      a1 += __shfl_xor(a1, 16);  a1 += __shfl_xor(a1, 32);
      a2 += __shfl_xor(a2, 16);  a2 += __shfl_xor(a2, 32);

      if (g == 0) {
        const int j = j0 + c16;
        if (i < j) {
          float sym = 0.5f * (ftanh(a1 + b2) + ftanh(a2 + b2));
          drow[(long)i * N_ + j] = sym;
          drow[(long)j * N_ + i] = sym;
        } else if (i == j) {
          drow[(long)i * N_ + i] = 0.f;
        }
      }
    }
    __syncthreads();
  }

  grid_barrier(bar + 1);

  // ===================== Phase C: normalize rows =====================
  const float lam = 1.f / (1.f + expf(-raw_lambda[0]));
  for (int rr = blockIdx.x; rr < NROWS; rr += GRID_) {
    const int i = rr % N_;
    const float* arow = a_static + (long)i * N_;
    float* drow = out + (long)rr * N_;

    float vals[3];
    float s = 0.f;
    #pragma unroll
    for (int r = 0; r < 3; ++r) {
      int j = r * 256 + tid;
      float v = arow[j] + lam * drow[j];
      v = fmaxf(v, 0.f);
      vals[r] = v;
      s += v;
    }
    s = wave_sum64(s);
    if (lane == 0) sh.n.ps[w] = s;
    __syncthreads();
    float tot = sh.n.ps[0] + sh.n.ps[1] + sh.n.ps[2] + sh.n.ps[3];
    float inv = 1.f / fmaxf(tot, 1e-6f);
    #pragma unroll
    for (int r = 0; r < 3; ++r) {
      int j = r * 256 + tid;
      drow[j] = vals[r] * inv;
    }
    if (rr == 0 && tid == 0) out[(long)B_ * N_ * N_] = lam;
    __syncthreads();
  }
}

// ---------------------------------------------------------------------------
extern "C" void kernel_launch(void* const* d_in, const int* in_sizes, int n_in,
                              void* d_out, int out_size, void* d_ws, size_t ws_size,
                              hipStream_t stream) {
  const float* x_hist     = (const float*)d_in[0];
  const float* x_mark     = (const float*)d_in[1];
  const float* a_static   = (const float*)d_in[2];
  const float* te_w1      = (const float*)d_in[3];
  const float* te_b1      = (const float*)d_in[4];
  const float* te_w2      = (const float*)d_in[5];
  const float* te_b2      = (const float*)d_in[6];
  const float* me_w1      = (const float*)d_in[7];
  const float* me_b1      = (const float*)d_in[8];
  const float* me_w2      = (const float*)d_in[9];
  const float* me_b2      = (const float*)d_in[10];
  const float* nf_w       = (const float*)d_in[11];
  const float* nf_b       = (const float*)d_in[12];
  const float* ps_w1      = (const float*)d_in[13];
  const float* ps_b1      = (const float*)d_in[14];
  const float* ps_w2      = (const float*)d_in[15];
  const float* ps_b2      = (const float*)d_in[16];
  const float* raw_lambda = (const float*)d_in[17];

  float* out = (float*)d_out;
  float* h   = (float*)d_ws;                 // B*N*64 f32
  float* si  = h  + (long)B_ * N_ * HID_;
  float* sj  = si + (long)B_ * N_ * HID_;
  unsigned short* wdf = (unsigned short*)(sj + (long)B_ * N_ * HID_);  // 4096 bf16
  unsigned int* bar   = (unsigned int*)(wdf + 4096);                   // 2 counters

  hipMemsetAsync((void*)bar, 0, 2 * sizeof(unsigned int), stream);

  mega_kernel<<<GRID_, 256, 0, stream>>>(
      x_hist, x_mark, te_w1, te_b1, te_w2, te_b2,
      me_w1, me_b1, me_w2, me_b2, nf_w, nf_b,
      ps_w1, ps_b1, ps_w2, ps_b2, raw_lambda, a_static,
      out, h, si, sj, wdf, bar);
}

// Round 9
// 48.389 us; speedup vs baseline: 7.5938x; 7.5938x over previous
//
#include <hip/hip_runtime.h>
#include <hip/hip_bf16.h>
#include <math.h>

#define B_ 2
#define N_ 768
#define T_ 96
#define FM_ 8
#define HID_ 64
#define TD_ 32
#define MD_ 32
#define TILE 16
#define TI32 32
#define NTILES (N_/TILE)            // 48
#define PERB 600                    // sum_{a=0}^{23} (48-2a)

typedef __attribute__((ext_vector_type(8))) short short8v;
typedef __attribute__((ext_vector_type(8))) unsigned short ushort8v;
typedef __attribute__((ext_vector_type(4))) float f32x4;
typedef __attribute__((ext_vector_type(2))) float f32x2;

__device__ __forceinline__ float ftanh(float x){
  float e = __expf(2.f * x);
  return 1.f - 2.f * __builtin_amdgcn_rcpf(e + 1.f);
}

__device__ __forceinline__ float wave_sum64(float v){
  #pragma unroll
  for (int m = 32; m; m >>= 1) v += __shfl_xor(v, m);
  return v;
}
__device__ __forceinline__ float wave_max64(float v){
  #pragma unroll
  for (int m = 32; m; m >>= 1) v = fmaxf(v, __shfl_xor(v, m));
  return v;
}

// ---------------------------------------------------------------------------
// Kernel 1: per-(b,n) features. 4 rows/block (4 waves). Outputs:
//   hbf[row][64]  : bf16(h)
//   siq[row][64]  : float2 {P,Q} = {s_i + u, s_j + u},  u = h @ bf16(W_d)
// Blocks [384,386): pack W_d into bf16 B-fragments wdf (q=(blk-384)*4+wave).
// ---------------------------------------------------------------------------
__global__ __launch_bounds__(256) void feat_kernel(
    const float* __restrict__ x_hist, const float* __restrict__ x_mark,
    const float* __restrict__ te_w1, const float* __restrict__ te_b1,
    const float* __restrict__ te_w2, const float* __restrict__ te_b2,
    const float* __restrict__ me_w1, const float* __restrict__ me_b1,
    const float* __restrict__ me_w2, const float* __restrict__ me_b2,
    const float* __restrict__ nf_w,  const float* __restrict__ nf_b,
    const float* __restrict__ ps_w1,
    unsigned short* __restrict__ hbf, f32x2* __restrict__ siq,
    unsigned short* __restrict__ wdf)
{
  const int tid  = threadIdx.x;
  const int lane = tid & 63;
  const int w    = tid >> 6;
  const int NB   = (B_ * N_) / 4;       // 384

  if (blockIdx.x >= NB) {               // W_d packing blocks
    const int q  = (blockIdx.x - NB) * 4 + w;   // 0..7 = nt*2+s
    const int nt = q >> 1, s = q & 1;
    const int col = (lane & 15) + 16 * nt;
    const int k0  = s * 32 + ((lane >> 4) << 3);
    #pragma unroll
    for (int jj = 0; jj < 8; ++jj) {
      float v = ps_w1[(2 * HID_ + k0 + jj) * HID_ + col];
      __hip_bfloat16 bv = __float2bfloat16(v);
      unsigned short us;
      __builtin_memcpy(&us, &bv, 2);
      wdf[(q * 64 + lane) * 8 + jj] = us;
    }
    return;
  }

  const int row = blockIdx.x * 4 + w;   // b*N + n

  __shared__ float st [4][3];
  __shared__ float ms [4][FM_];
  __shared__ float t1s[4][TD_];
  __shared__ float m1s[4][MD_];
  __shared__ float hc [4][HID_];
  __shared__ float hs [4][HID_];

  const float* xh = x_hist + (long)row * T_;
  float s  = xh[lane];
  float mx = s;
  if (lane < T_ - 64) { float v = xh[lane + 64]; s += v; mx = fmaxf(mx, v); }
  s  = wave_sum64(s);
  mx = wave_max64(mx);
  if (lane == 0) { st[w][0] = xh[T_ - 1]; st[w][1] = s * (1.0f / T_); st[w][2] = mx; }

  const float* xm = x_mark + (long)row * T_ * FM_;
  float msv = 0.f;
  #pragma unroll
  for (int k = 0; k < 12; ++k) msv += xm[lane + 64 * k];
  msv += __shfl_xor(msv, 8);
  msv += __shfl_xor(msv, 16);
  msv += __shfl_xor(msv, 32);
  if (lane < FM_) ms[w][lane] = msv * (1.0f / T_);
  __syncthreads();

  if (lane < TD_) {
    float a = te_b1[lane];
    #pragma unroll
    for (int k = 0; k < 3; ++k) a += st[w][k] * te_w1[k * TD_ + lane];
    t1s[w][lane] = fmaxf(a, 0.f);
    float am = me_b1[lane];
    #pragma unroll
    for (int k = 0; k < FM_; ++k) am += ms[w][k] * me_w1[k * MD_ + lane];
    m1s[w][lane] = fmaxf(am, 0.f);
  }
  __syncthreads();
  if (lane < TD_) {
    float a = te_b2[lane];
    #pragma unroll
    for (int k = 0; k < TD_; ++k) a += t1s[w][k] * te_w2[k * TD_ + lane];
    hc[w][lane] = a;
    float am = me_b2[lane];
    #pragma unroll
    for (int k = 0; k < MD_; ++k) am += m1s[w][k] * me_w2[k * MD_ + lane];
    hc[w][TD_ + lane] = am;
  }
  __syncthreads();
  {
    float a = nf_b[lane];
    #pragma unroll
    for (int k = 0; k < HID_; ++k) a += hc[w][k] * nf_w[k * HID_ + lane];
    float hv = fmaxf(a, 0.f);
    hs[w][lane] = hv;
    __hip_bfloat16 hb = __float2bfloat16(hv);
    unsigned short us;
    __builtin_memcpy(&us, &hb, 2);
    hbf[(long)row * HID_ + lane] = us;
  }
  __syncthreads();
  {
    float a1 = 0.f, a2 = 0.f, u = 0.f;
    #pragma unroll
    for (int k = 0; k < HID_; ++k) {
      float hv = hs[w][k];
      a1 += hv * ps_w1[k * HID_ + lane];
      a2 += hv * ps_w1[(HID_ + k) * HID_ + lane];
      float wv = ps_w1[(2 * HID_ + k) * HID_ + lane];
      __hip_bfloat16 wb = __float2bfloat16(wv);     // same rounding as wdf
      u += hv * __bfloat162float(wb);
    }
    siq[(long)row * HID_ + lane] = (f32x2){a1 + u, a2 + u};
  }
}

// ---------------------------------------------------------------------------
// Kernel 2: pairwise delta. |hi-hj| = hi+hj-2min  ->  rank-1 (in P,Q) +
// MFMA on min(hi,hj) in bf16 (packed u16 min; h>=0 so bit-order = value-order).
// Block = 32 i-rows x 16 j-rows, 4 waves; wave w owns i-rows 8w..8w+7.
//   pre(i,j)_c = P(i)_c + [Q(j)_c + b1_c] - 2*minacc_c
//   pre(j,i)_c = Q(i)_c + [P(j)_c + b1_c] - 2*minacc_c
// ---------------------------------------------------------------------------
__global__ __launch_bounds__(256, 4) void pair_kernel(
    const unsigned short* __restrict__ hbf, const f32x2* __restrict__ siq,
    const float* __restrict__ ps_b1, const float* __restrict__ ps_w2,
    const float* __restrict__ ps_b2, const unsigned short* __restrict__ wdf,
    float* __restrict__ delta)
{
  int bidx = blockIdx.x;
  int b = bidx / PERB;
  int t = bidx % PERB;
  int a = 0;
  while (t >= NTILES - 2 * a) { t -= NTILES - 2 * a; ++a; }
  int tJ = 2 * a + t;
  const int i0 = a * TI32, j0 = tJ * TILE;

  __shared__ unsigned short hIbf[TI32][HID_];   // 4 KB, broadcast reads
  __shared__ unsigned short hJbf[TILE][72];     // 2.25 KB, padded rows
  __shared__ f32x2 SI2[TI32][HID_];             // 16 KB {P,Q}
  __shared__ f32x2 SJ2[TILE][66];               // 8.25 KB {Q+b1, P+b1}

  const int tid  = threadIdx.x;
  const int lane = tid & 63;
  const int w    = tid >> 6;

  // ---- staging: all b128 ----
  {
    const int r8 = tid >> 3;        // 0..31
    const int ch = tid & 7;         // 0..7 (16B chunks)
    const long gri = (long)(b * N_ + i0 + r8) * HID_;
    *(ushort8v*)&hIbf[r8][8 * ch] = *(const ushort8v*)(hbf + gri + 8 * ch);
    const f32x4* sp = (const f32x4*)(siq + gri + 8 * ch);
    f32x4* dp = (f32x4*)&SI2[r8][8 * ch];
    dp[0] = sp[0]; dp[1] = sp[1]; dp[2] = sp[2]; dp[3] = sp[3];

    if (tid < 128) {
      const int rj = tid >> 3;      // 0..15
      const long grj = (long)(b * N_ + j0 + rj) * HID_;
      *(ushort8v*)&hJbf[rj][8 * ch] = *(const ushort8v*)(hbf + grj + 8 * ch);
      const f32x4* sj = (const f32x4*)(siq + grj + 8 * ch);
      const f32x4 b4a = *(const f32x4*)(ps_b1 + 8 * ch);
      const f32x4 b4b = *(const f32x4*)(ps_b1 + 8 * ch + 4);
      f32x4 v0 = sj[0], v1 = sj[1], v2 = sj[2], v3 = sj[3];
      f32x4 o0 = {v0[1] + b4a[0], v0[0] + b4a[0], v0[3] + b4a[1], v0[2] + b4a[1]};
      f32x4 o1 = {v1[1] + b4a[2], v1[0] + b4a[2], v1[3] + b4a[3], v1[2] + b4a[3]};
      f32x4 o2 = {v2[1] + b4b[0], v2[0] + b4b[0], v2[3] + b4b[1], v2[2] + b4b[1]};
      f32x4 o3 = {v3[1] + b4b[2], v3[0] + b4b[2], v3[3] + b4b[3], v3[2] + b4b[3]};
      f32x4* dj = (f32x4*)&SJ2[rj][8 * ch];
      dj[0] = o0; dj[1] = o1; dj[2] = o2; dj[3] = o3;
    }
  }
  const float b2 = ps_b2[0];
  __syncthreads();

  const int g   = lane >> 4;     // 0..3
  const int c16 = lane & 15;     // = j within tile

  // Wd fragments (A operand), prepacked
  short8v wfr[8];
  const short8v* wdp = (const short8v*)wdf;
  #pragma unroll
  for (int q = 0; q < 8; ++q) wfr[q] = wdp[q * 64 + lane];

  // hoists (m-invariant)
  ushort8v hj0 = *(const ushort8v*)&hJbf[c16][8 * g];        // s=0: k=8g..8g+7
  ushort8v hj1 = *(const ushort8v*)&hJbf[c16][32 + 8 * g];   // s=1
  f32x2 sJ2h[16];
  f32x4 w24[4];
  #pragma unroll
  for (int mt = 0; mt < 4; ++mt) {
    const int cb = 16 * mt + 4 * g;
    f32x4 u0 = *(const f32x4*)&SJ2[c16][cb];
    f32x4 u1 = *(const f32x4*)&SJ2[c16][cb + 2];
    sJ2h[mt*4+0] = (f32x2){u0[0], u0[1]};
    sJ2h[mt*4+1] = (f32x2){u0[2], u0[3]};
    sJ2h[mt*4+2] = (f32x2){u1[0], u1[1]};
    sJ2h[mt*4+3] = (f32x2){u1[2], u1[3]};
    w24[mt] = *(const f32x4*)(ps_w2 + cb);
  }

  float* drow = delta + (long)b * N_ * N_;

  #pragma unroll
  for (int m = 0; m < 8; ++m) {
    const int iloc = w * 8 + m;
    const int i = i0 + iloc;

    // A(B-operand) build: min(hi, hj) in bf16 via packed u16 min
    ushort8v hi0 = *(const ushort8v*)&hIbf[iloc][8 * g];
    ushort8v hi1 = *(const ushort8v*)&hIbf[iloc][32 + 8 * g];
    short8v af0 = __builtin_bit_cast(short8v, __builtin_elementwise_min(hi0, hj0));
    short8v af1 = __builtin_bit_cast(short8v, __builtin_elementwise_min(hi1, hj1));

    f32x4 acc[4];
    #pragma unroll
    for (int mt = 0; mt < 4; ++mt) acc[mt] = (f32x4){0.f, 0.f, 0.f, 0.f};
    #pragma unroll
    for (int mt = 0; mt < 4; ++mt) {
      acc[mt] = __builtin_amdgcn_mfma_f32_16x16x32_bf16(wfr[2 * mt + 0], af0, acc[mt], 0, 0, 0);
      acc[mt] = __builtin_amdgcn_mfma_f32_16x16x32_bf16(wfr[2 * mt + 1], af1, acc[mt], 0, 0, 0);
    }

    // packed epilogue: lane holds j=c16, c = 16mt + 4g + r
    f32x2 acc2 = (f32x2){0.f, 0.f};
    #pragma unroll
    for (int mt = 0; mt < 4; ++mt) {
      const int cb = 16 * mt + 4 * g;
      f32x4 s01 = *(const f32x4*)&SI2[iloc][cb];       // pairs r=0,1 (broadcast)
      f32x4 s23 = *(const f32x4*)&SI2[iloc][cb + 2];   // pairs r=2,3
      #pragma unroll
      for (int r = 0; r < 4; ++r) {
        f32x2 siv = (r < 2) ? (f32x2){s01[2*r], s01[2*r+1]}
                            : (f32x2){s23[2*(r-2)], s23[2*(r-2)+1]};
        float av = acc[mt][r];
        f32x2 pre = siv + sJ2h[mt*4+r];
        pre = pre + (f32x2){-2.f * av, -2.f * av};
        pre = __builtin_elementwise_max(pre, (f32x2){0.f, 0.f});
        f32x2 w22 = (f32x2){w24[mt][r], w24[mt][r]};
        acc2 = acc2 + pre * w22;
      }
    }
    float a1 = acc2[0], a2 = acc2[1];
    a1 += __shfl_xor(a1, 16);  a1 += __shfl_xor(a1, 32);
    a2 += __shfl_xor(a2, 16);  a2 += __shfl_xor(a2, 32);

    if (g == 0) {
      const int j = j0 + c16;
      if (i < j) {
        float sym = 0.5f * (ftanh(a1 + b2) + ftanh(a2 + b2));
        drow[(long)i * N_ + j] = sym;
        drow[(long)j * N_ + i] = sym;
      } else if (i == j) {
        drow[(long)i * N_ + i] = 0.f;
      }
    }
  }
}

// ---------------------------------------------------------------------------
// Kernel 3: a_hybrid = relu(a_static + lam*delta) row-normalized, in place.
// ---------------------------------------------------------------------------
__global__ __launch_bounds__(256) void norm_kernel(
    const float* __restrict__ a_static, const float* __restrict__ raw_lambda,
    float* __restrict__ out)
{
  const int row = blockIdx.x;           // b*N + i
  const int i   = row % N_;
  const int tid = threadIdx.x;
  const float lam = 1.f / (1.f + expf(-raw_lambda[0]));

  const float* arow = a_static + (long)i * N_;
  float* drow = out + (long)row * N_;

  float vals[3];
  float s = 0.f;
  #pragma unroll
  for (int r = 0; r < 3; ++r) {
    int j = r * 256 + tid;
    float v = arow[j] + lam * drow[j];
    v = fmaxf(v, 0.f);
    vals[r] = v;
    s += v;
  }
  s = wave_sum64(s);
  __shared__ float ps[4];
  if ((tid & 63) == 0) ps[tid >> 6] = s;
  __syncthreads();
  float tot = ps[0] + ps[1] + ps[2] + ps[3];
  float inv = 1.f / fmaxf(tot, 1e-6f);
  #pragma unroll
  for (int r = 0; r < 3; ++r) {
    int j = r * 256 + tid;
    drow[j] = vals[r] * inv;
  }
  if (row == 0 && tid == 0) out[(long)B_ * N_ * N_] = lam;
}

// ---------------------------------------------------------------------------
extern "C" void kernel_launch(void* const* d_in, const int* in_sizes, int n_in,
                              void* d_out, int out_size, void* d_ws, size_t ws_size,
                              hipStream_t stream) {
  const float* x_hist     = (const float*)d_in[0];
  const float* x_mark     = (const float*)d_in[1];
  const float* a_static   = (const float*)d_in[2];
  const float* te_w1      = (const float*)d_in[3];
  const float* te_b1      = (const float*)d_in[4];
  const float* te_w2      = (const float*)d_in[5];
  const float* te_b2      = (const float*)d_in[6];
  const float* me_w1      = (const float*)d_in[7];
  const float* me_b1      = (const float*)d_in[8];
  const float* me_w2      = (const float*)d_in[9];
  const float* me_b2      = (const float*)d_in[10];
  const float* nf_w       = (const float*)d_in[11];
  const float* nf_b       = (const float*)d_in[12];
  const float* ps_w1      = (const float*)d_in[13];
  const float* ps_b1      = (const float*)d_in[14];
  const float* ps_w2      = (const float*)d_in[15];
  const float* ps_b2      = (const float*)d_in[16];
  const float* raw_lambda = (const float*)d_in[17];

  float* out = (float*)d_out;
  char* ws = (char*)d_ws;
  unsigned short* hbf = (unsigned short*)ws;                     // 1536*64 bf16 = 196608 B
  f32x2* siq          = (f32x2*)(ws + 196608);                   // 1536*64 float2 = 786432 B
  unsigned short* wdf = (unsigned short*)(ws + 196608 + 786432); // 4096 bf16

  feat_kernel<<<(B_ * N_) / 4 + 2, 256, 0, stream>>>(
      x_hist, x_mark, te_w1, te_b1, te_w2, te_b2,
      me_w1, me_b1, me_w2, me_b2, nf_w, nf_b, ps_w1, hbf, siq, wdf);

  pair_kernel<<<B_ * PERB, 256, 0, stream>>>(
      hbf, siq, ps_b1, ps_w2, ps_b2, wdf, out);

  norm_kernel<<<B_ * N_, 256, 0, stream>>>(a_static, raw_lambda, out);
}